// Round 1
// baseline (1284.284 us; speedup 1.0000x reference)
//
#include <hip/hip_runtime.h>

// ---------- types ----------
typedef __attribute__((ext_vector_type(4))) float f32x4;
typedef __attribute__((ext_vector_type(8))) short s16x8;
typedef __attribute__((ext_vector_type(4))) short s16x4;

// ---------- problem dims (fixed) ----------
constexpr int DB   = 2;
constexpr int DS   = 2048;
constexpr int DHID = 1024;
constexpr int DNH  = 16;
constexpr int DHD  = 64;
constexpr int GM = DB * DS;   // 4096 rows for all projections
constexpr int GN = DHID;      // 1024
constexpr int GK = DHID;      // 1024

// ---------- bf16 helpers (RNE) ----------
__device__ __forceinline__ unsigned short f2bf_bits(float x) {
  unsigned int u = __float_as_uint(x);
  u += 0x7fffu + ((u >> 16) & 1u);
  return (unsigned short)(u >> 16);
}
__device__ __forceinline__ float bf2f(unsigned short b) {
  return __uint_as_float(((unsigned int)b) << 16);
}
__device__ __forceinline__ void split2(float x, unsigned short &h, unsigned short &l) {
  unsigned short hb = f2bf_bits(x);
  h = hb;
  l = f2bf_bits(x - bf2f(hb));
}

// =====================================================================
// GEMM: C[m][n] = sum_k A[m][k] * W[n][k] + bias[n]
// MODE 0: split hi/lo input (3-term MFMA), store bf16 hi+lo   (Q, K proj)
// MODE 1: single bf16, store bf16                             (V proj)
// MODE 2: single bf16, store fp32                             (output proj)
// tile 128x128, BK=32, 256 threads (4 waves, each 64x64)
// =====================================================================
template<int MODE>
__global__ __launch_bounds__(256) void gemm_x(
    const float* __restrict__ A, const float* __restrict__ W, const float* __restrict__ bias,
    unsigned short* __restrict__ o_hi, unsigned short* __restrict__ o_lo, float* __restrict__ o_f)
{
  constexpr int BK  = 32;
  constexpr int LDA = BK + 8;   // +16B pad: frag reads land 2-way max (free)
  __shared__ unsigned short Ah[128][LDA];
  __shared__ unsigned short Bh[128][LDA];
  __shared__ unsigned short Al[(MODE == 0) ? 128 : 1][LDA];
  __shared__ unsigned short Bl[(MODE == 0) ? 128 : 1][LDA];

  const int t    = threadIdx.x;
  const int lane = t & 63;
  const int wave = t >> 6;
  const int quad = lane >> 4;
  const int l16  = lane & 15;
  const int m0 = blockIdx.y * 128;
  const int n0 = blockIdx.x * 128;
  const int wr = (wave >> 1) * 64;
  const int wc = (wave & 1) * 64;
  const int sr  = t >> 3;        // 0..31
  const int sc4 = (t & 7) * 4;   // 0..28

  f32x4 acc[4][4];
#pragma unroll
  for (int i = 0; i < 4; i++)
#pragma unroll
    for (int j = 0; j < 4; j++) acc[i][j] = (f32x4){0.f, 0.f, 0.f, 0.f};

  for (int k0 = 0; k0 < GK; k0 += BK) {
    // ---- stage fp32 -> bf16(hi/lo) into LDS ----
#pragma unroll
    for (int i = 0; i < 4; i++) {
      int r = sr + i * 32;
      f32x4 va = *(const f32x4*)(A + (size_t)(m0 + r) * GK + k0 + sc4);
      f32x4 vb = *(const f32x4*)(W + (size_t)(n0 + r) * GK + k0 + sc4);
      s16x4 ah, al, bh, bl;
#pragma unroll
      for (int e = 0; e < 4; e++) {
        unsigned short hh, ll;
        split2(va[e], hh, ll); ah[e] = (short)hh; al[e] = (short)ll;
        split2(vb[e], hh, ll); bh[e] = (short)hh; bl[e] = (short)ll;
      }
      *(s16x4*)&Ah[r][sc4] = ah;
      *(s16x4*)&Bh[r][sc4] = bh;
      if constexpr (MODE == 0) {
        *(s16x4*)&Al[r][sc4] = al;
        *(s16x4*)&Bl[r][sc4] = bl;
      }
    }
    __syncthreads();

    // ---- fragments + MFMA ----
    s16x8 af[4], bf[4], afl[4], bfl[4];
#pragma unroll
    for (int i = 0; i < 4; i++) {
      af[i] = *(const s16x8*)&Ah[wr + i * 16 + l16][quad * 8];
      bf[i] = *(const s16x8*)&Bh[wc + i * 16 + l16][quad * 8];
      if constexpr (MODE == 0) {
        afl[i] = *(const s16x8*)&Al[wr + i * 16 + l16][quad * 8];
        bfl[i] = *(const s16x8*)&Bl[wc + i * 16 + l16][quad * 8];
      }
    }
#pragma unroll
    for (int i = 0; i < 4; i++)
#pragma unroll
      for (int j = 0; j < 4; j++) {
        acc[i][j] = __builtin_amdgcn_mfma_f32_16x16x32_bf16(af[i], bf[j], acc[i][j], 0, 0, 0);
        if constexpr (MODE == 0) {
          acc[i][j] = __builtin_amdgcn_mfma_f32_16x16x32_bf16(af[i],  bfl[j], acc[i][j], 0, 0, 0);
          acc[i][j] = __builtin_amdgcn_mfma_f32_16x16x32_bf16(afl[i], bf[j],  acc[i][j], 0, 0, 0);
        }
      }
    __syncthreads();
  }

  // ---- epilogue: C/D layout col=lane&15, row=quad*4+reg ----
#pragma unroll
  for (int j = 0; j < 4; j++) {
    int n = n0 + wc + j * 16 + l16;
    float bj = bias[n];
#pragma unroll
    for (int i = 0; i < 4; i++) {
      int mbase = m0 + wr + i * 16 + quad * 4;
#pragma unroll
      for (int r = 0; r < 4; r++) {
        float v = acc[i][j][r] + bj;
        size_t off = (size_t)(mbase + r) * GN + n;
        if constexpr (MODE == 0) {
          unsigned short hb, lb; split2(v, hb, lb);
          o_hi[off] = hb; o_lo[off] = lb;
        } else if constexpr (MODE == 1) {
          o_hi[off] = f2bf_bits(v);
        } else {
          o_f[off] = v;
        }
      }
    }
  }
}

// =====================================================================
// V (B,S,HID) bf16 -> Vt (B,NH,HD,S) bf16 so PV B-fragments are contiguous
// =====================================================================
__global__ __launch_bounds__(256) void transpose_v(
    const unsigned short* __restrict__ V, unsigned short* __restrict__ Vt)
{
  __shared__ unsigned short tile[64][72];
  const int t   = threadIdx.x;
  const int blk = blockIdx.x;           // B*NH*(S/64) = 1024
  const int st  = blk & 31;
  const int bh  = blk >> 5;             // 0..31
  const int b = bh >> 4, h = bh & 15;

  const int sr = t >> 3, d8 = (t & 7) * 8;
#pragma unroll
  for (int i = 0; i < 2; i++) {
    int s = sr + i * 32;
    s16x8 v = *(const s16x8*)&V[((size_t)(b * DS + st * 64 + s)) * DHID + h * DHD + d8];
#pragma unroll
    for (int j = 0; j < 8; j++) tile[d8 + j][s] = (unsigned short)v[j];
  }
  __syncthreads();
  const int dr = t >> 3, s8 = (t & 7) * 8;
#pragma unroll
  for (int i = 0; i < 2; i++) {
    int d = dr + i * 32;
    s16x8 u = *(const s16x8*)&tile[d][s8];
    *(s16x8*)&Vt[((size_t)bh * DHD + d) * DS + st * 64 + s8] = u;
  }
}

// =====================================================================
// Fused attention: one WG per (b, h, 16 q-rows). 512 threads (8 waves).
// Full 16 x 2048 fp32 score rows live in dynamic LDS (135 KB).
//  phase 1: scores = split-bf16 QK^T * 0.125 + beta*ss, mask -> LDS
//  phase 2: fp32 softmax; write normalized weights (float4, coalesced);
//           keep unnormalized exp in LDS; 1/l in stats[]
//  phase 3: PV (single bf16), split-K across wave pairs, scale by 1/l
// =====================================================================
constexpr int SCPAD = 2052;  // fp32 row stride: 2-way LDS bank aliasing max (free)

__global__ __launch_bounds__(512) void attn_kernel(
    const unsigned short* __restrict__ Qhi, const unsigned short* __restrict__ Qlo,
    const unsigned short* __restrict__ Khi, const unsigned short* __restrict__ Klo,
    const unsigned short* __restrict__ Vt,
    const float* __restrict__ ssim, const int* __restrict__ amask,
    const float* __restrict__ betap,
    float* __restrict__ wout, float* __restrict__ outf)
{
  extern __shared__ float sm[];
  float* sc      = sm;                   // 16 * 2052
  float* partial = sm + 16 * SCPAD;      // 4 * 256
  float* stats   = partial + 1024;       // 16

  const int t    = threadIdx.x;
  const int lane = t & 63;
  const int wave = t >> 6;
  const int quad = lane >> 4;
  const int l16  = lane & 15;

  const int blk = blockIdx.x;            // 4096
  const int qt = blk & 127;
  const int h  = (blk >> 7) & 15;
  const int b  = blk >> 11;
  const int q0 = qt * 16;
  const size_t qkvBase = (size_t)b * DS * DHID + h * DHD;
  const float beta = *betap;

  // ---- Q fragments (A-operand: m=lane&15, k=quad*8+j), hi & lo, 2 k-steps ----
  s16x8 qh[2], ql[2];
  {
    size_t ro = qkvBase + (size_t)(q0 + l16) * DHID + quad * 8;
    qh[0] = *(const s16x8*)(Qhi + ro);
    ql[0] = *(const s16x8*)(Qlo + ro);
    qh[1] = *(const s16x8*)(Qhi + ro + 32);
    ql[1] = *(const s16x8*)(Qlo + ro + 32);
  }

  // ---- phase 1: scores ----
  for (int i = 0; i < 16; i++) {
    int nb  = wave + 8 * i;          // 8 waves x 16 = 128 n-blocks
    int kc0 = nb * 16;
    size_t ko = qkvBase + (size_t)(kc0 + l16) * DHID + quad * 8;
    s16x8 kh0 = *(const s16x8*)(Khi + ko);
    s16x8 kl0 = *(const s16x8*)(Klo + ko);
    s16x8 kh1 = *(const s16x8*)(Khi + ko + 32);
    s16x8 kl1 = *(const s16x8*)(Klo + ko + 32);
    f32x4 a = (f32x4){0.f, 0.f, 0.f, 0.f};
    a = __builtin_amdgcn_mfma_f32_16x16x32_bf16(qh[0], kh0, a, 0, 0, 0);
    a = __builtin_amdgcn_mfma_f32_16x16x32_bf16(qh[1], kh1, a, 0, 0, 0);
    a = __builtin_amdgcn_mfma_f32_16x16x32_bf16(qh[0], kl0, a, 0, 0, 0);
    a = __builtin_amdgcn_mfma_f32_16x16x32_bf16(qh[1], kl1, a, 0, 0, 0);
    a = __builtin_amdgcn_mfma_f32_16x16x32_bf16(ql[0], kh0, a, 0, 0, 0);
    a = __builtin_amdgcn_mfma_f32_16x16x32_bf16(ql[1], kh1, a, 0, 0, 0);

    int kcol = kc0 + l16;
    int mk = amask[b * DS + kcol];
#pragma unroll
    for (int r = 0; r < 4; r++) {
      int qr = quad * 4 + r;                    // C/D: row = quad*4+reg
      float s = a[r] * 0.125f;                  // 1/sqrt(64)
      s += beta * ssim[((size_t)b * DS + q0 + qr) * DS + kcol];
      s = mk ? s : -1e30f;
      sc[qr * SCPAD + kcol] = s;
    }
  }
  __syncthreads();

  // ---- phase 2: softmax over 2048, 32 lanes per row ----
  {
    int r = t >> 5, l32 = t & 31;
    float m = -3.0e38f;
#pragma unroll
    for (int i = 0; i < 16; i++) {
      f32x4 v = *(f32x4*)&sc[r * SCPAD + l32 * 4 + i * 128];
      m = fmaxf(m, fmaxf(fmaxf(v[0], v[1]), fmaxf(v[2], v[3])));
    }
    for (int o = 1; o < 32; o <<= 1) m = fmaxf(m, __shfl_xor(m, o));
    float lsum = 0.f;
#pragma unroll
    for (int i = 0; i < 16; i++) {
      f32x4* p = (f32x4*)&sc[r * SCPAD + l32 * 4 + i * 128];
      f32x4 v = *p;
      v[0] = __expf(v[0] - m); v[1] = __expf(v[1] - m);
      v[2] = __expf(v[2] - m); v[3] = __expf(v[3] - m);
      *p = v;
      lsum += (v[0] + v[1]) + (v[2] + v[3]);
    }
    for (int o = 1; o < 32; o <<= 1) lsum += __shfl_xor(lsum, o);
    float rinv = 1.0f / lsum;
    if (l32 == 0) stats[r] = rinv;
    size_t wbase = (((size_t)b * DNH + h) * DS + q0 + r) * DS;
#pragma unroll
    for (int i = 0; i < 16; i++) {
      f32x4 v = *(f32x4*)&sc[r * SCPAD + l32 * 4 + i * 128];
      v *= rinv;
      *(f32x4*)&wout[wbase + l32 * 4 + i * 128] = v;
    }
  }
  __syncthreads();

  // ---- phase 3: PV. wave: n-block = wave&3 (16 d cols), k-half = wave>>2 ----
  const int nb = wave & 3;
  const int khf = wave >> 2;
  f32x4 acc = (f32x4){0.f, 0.f, 0.f, 0.f};
  {
    size_t vbase = (((size_t)b * DNH + h) * DHD + nb * 16 + l16) * DS;
    for (int ks = 0; ks < 32; ks++) {
      int k = khf * 1024 + ks * 32 + quad * 8;
      f32x4 p0 = *(f32x4*)&sc[l16 * SCPAD + k];
      f32x4 p1 = *(f32x4*)&sc[l16 * SCPAD + k + 4];
      s16x8 pa;
      pa[0] = (short)f2bf_bits(p0[0]); pa[1] = (short)f2bf_bits(p0[1]);
      pa[2] = (short)f2bf_bits(p0[2]); pa[3] = (short)f2bf_bits(p0[3]);
      pa[4] = (short)f2bf_bits(p1[0]); pa[5] = (short)f2bf_bits(p1[1]);
      pa[6] = (short)f2bf_bits(p1[2]); pa[7] = (short)f2bf_bits(p1[3]);
      s16x8 vb = *(const s16x8*)(Vt + vbase + k);
      acc = __builtin_amdgcn_mfma_f32_16x16x32_bf16(pa, vb, acc, 0, 0, 0);
    }
  }
  if (wave >= 4) {
#pragma unroll
    for (int r = 0; r < 4; r++)
      partial[nb * 256 + (quad * 4 + r) * 16 + l16] = acc[r];
  }
  __syncthreads();
  if (wave < 4) {
#pragma unroll
    for (int r = 0; r < 4; r++) {
      int qr = quad * 4 + r;
      float v = (acc[r] + partial[nb * 256 + qr * 16 + l16]) * stats[qr];
      outf[((size_t)b * DS + q0 + qr) * DHID + h * DHD + nb * 16 + l16] = v;
    }
  }
}

// =====================================================================
// launch
// =====================================================================
extern "C" void kernel_launch(void* const* d_in, const int* in_sizes, int n_in,
                              void* d_out, int out_size, void* d_ws, size_t ws_size,
                              hipStream_t stream) {
  (void)in_sizes; (void)n_in; (void)out_size; (void)ws_size;
  const float* qin  = (const float*)d_in[0];
  const float* kin  = (const float*)d_in[1];
  const float* vin  = (const float*)d_in[2];
  const int*   amask = (const int*)d_in[3];
  const float* ssim = (const float*)d_in[4];
  const float* Wq = (const float*)d_in[5];
  const float* bq = (const float*)d_in[6];
  const float* Wk = (const float*)d_in[7];
  const float* bk = (const float*)d_in[8];
  const float* Wv = (const float*)d_in[9];
  const float* bv = (const float*)d_in[10];
  const float* Wo = (const float*)d_in[11];
  const float* bo = (const float*)d_in[12];
  const float* beta = (const float*)d_in[13];

  // workspace carve: 6 x 8MB bf16 + 16MB fp32 = 64 MB
  constexpr size_t NE = (size_t)GM * GN;   // 4096*1024
  char* ws = (char*)d_ws;
  unsigned short* QhiW = (unsigned short*)ws;
  unsigned short* QloW = QhiW + NE;
  unsigned short* KhiW = QloW + NE;
  unsigned short* KloW = KhiW + NE;
  unsigned short* Vb   = KloW + NE;
  unsigned short* Vtr  = Vb + NE;
  float* OutF = (float*)(ws + 6 * NE * sizeof(unsigned short));

  float* outp = (float*)d_out;                 // (B,S,HID) fp32
  float* wout = outp + (size_t)DB * DS * DHID; // (B,NH,S,S) fp32

  dim3 gg(GN / 128, GM / 128);  // (8, 32)

  gemm_x<0><<<gg, 256, 0, stream>>>(qin, Wq, bq, QhiW, QloW, nullptr);
  gemm_x<0><<<gg, 256, 0, stream>>>(kin, Wk, bk, KhiW, KloW, nullptr);
  gemm_x<1><<<gg, 256, 0, stream>>>(vin, Wv, bv, Vb, nullptr, nullptr);
  transpose_v<<<DB * DNH * (DS / 64), 256, 0, stream>>>(Vb, Vtr);

  const int attnLds = (16 * SCPAD + 4 * 256 + 16) * 4;  // 135488 B
  attn_kernel<<<DB * DNH * (DS / 16), 512, attnLds, stream>>>(
      QhiW, QloW, KhiW, KloW, Vtr, ssim, amask, beta, wout, OutF);

  gemm_x<2><<<gg, 256, 0, stream>>>(OutF, Wo, bo, nullptr, nullptr, outp);
}